// Round 1
// baseline (285.899 us; speedup 1.0000x reference)
//
#include <hip/hip_runtime.h>

// B=8, C=16, H=W=384. Inputs (fp32): net_out, target, max_positiones.
// loss_bc = 0.05*m1/(d1+eps) + 0.95*m2/(d2+eps)
//   m1 = sum(d2*t), d1 = sum(t), m2 = sum(d2) - m1, d2den = HW - d1
// active_bc = !(max(t)==0 && max(mp)==0) -> mp scanned only if max(t)==0 (rare)
// img_loss_b = sum_c(losses)/count_nonzero(losses); out = mean_b.
//
// R7: FUSED single-kernel. Evidence from R6 rocprof: top-5 dispatches are all
// harness fillBufferAligned (~45us each); neither of our kernels exceeds 44.7us,
// yet dur_us=185 -> timed region is dominated by fixed harness poison fills.
// The R1-R6 "structure-insensitive cap" was this fixed overhead, not a HW load
// limit. Remaining controllable time: passA (24-45us) + final (~4us) + launch
// gap (~3us). This round removes the serial tail: final reduction is done by
// the last block to finish (threadfence + atomicAdd completion counter, the
// hipCUB device-reduce pattern: release = fence before atomic, acquire = fence
// after observing count). 4-byte memset node replaces the 2nd kernel launch.

typedef float f32x4 __attribute__((ext_vector_type(4)));

#define B_DIM 8
#define C_DIM 16
#define BC    (B_DIM * C_DIM)        // 128
#define HW    147456                 // 384*384
#define SEGS  16
#define SEG_ELEMS (HW / SEGS)        // 9216
#define TPB   256
#define F4PT  (SEG_ELEMS / 4 / TPB)  // 9 float4 per thread per array
#define NBLK  (BC * SEGS)            // 2048

#define ALPHA  0.05f
#define SMOOTH 1e-6f

// ws layout: float4 per block {sum_t, m1, sum_d2, mx_t}; then u32 counter.

__global__ __launch_bounds__(TPB, 2) void mismatch_fused(
    const float* __restrict__ net_out,
    const float* __restrict__ target,
    const float* __restrict__ maxp,
    float4* __restrict__ ws,
    unsigned int* __restrict__ counter,
    float* __restrict__ out)
{
    const int blk = blockIdx.x;                       // [0, NBLK)
    const size_t base4 = (size_t)blk * (SEG_ELEMS / 4);
    const int tid = threadIdx.x;

    const f32x4* __restrict__ t4 = (const f32x4*)target + base4;
    const f32x4* __restrict__ n4 = (const f32x4*)net_out + base4;

    float sum_t = 0.f, m1 = 0.f, sd2 = 0.f, mxt = 0.f;

#pragma unroll
    for (int k = 0; k < F4PT; ++k) {
        const int idx = k * TPB + tid;   // coalesced float4 access
        const f32x4 tv = __builtin_nontemporal_load(t4 + idx);
        const f32x4 nv = __builtin_nontemporal_load(n4 + idx);
#define ACC(c) { float t = tv.c, n = nv.c;                \
                 float d = t - n; float d2 = d * d;       \
                 sum_t += t; sd2 += d2;                   \
                 m1 = fmaf(d2, t, m1); mxt = fmaxf(mxt, t); }
        ACC(x) ACC(y) ACC(z) ACC(w)
#undef ACC
    }

    // wave (64-lane) reduction — order identical to R6 (absmax was 0.0)
#pragma unroll
    for (int off = 32; off > 0; off >>= 1) {
        sum_t += __shfl_down(sum_t, off);
        m1    += __shfl_down(m1, off);
        sd2   += __shfl_down(sd2, off);
        mxt    = fmaxf(mxt, __shfl_down(mxt, off));
    }

    __shared__ float s[4][4];
    __shared__ int s_last;
    const int wave = tid >> 6, lane = tid & 63;
    if (lane == 0) { s[wave][0] = sum_t; s[wave][1] = m1; s[wave][2] = sd2; s[wave][3] = mxt; }
    __syncthreads();
    if (tid == 0) {
        float4 o;
        o.x = s[0][0] + s[1][0] + s[2][0] + s[3][0];
        o.y = s[0][1] + s[1][1] + s[2][1] + s[3][1];
        o.z = s[0][2] + s[1][2] + s[2][2] + s[3][2];
        o.w = fmaxf(fmaxf(s[0][3], s[1][3]), fmaxf(s[2][3], s[3][3]));
        ws[blk] = o;
        __threadfence();                         // release: ws visible device-wide
        const unsigned int old = atomicAdd(counter, 1u);
        s_last = (old == (unsigned int)(NBLK - 1));
    }
    __syncthreads();
    if (!s_last) return;

    // ---- finisher: last block does the [B,C] reduction (code == old final) ----
    __threadfence();                             // acquire: see all blocks' ws

    __shared__ float losses[BC];
    __shared__ float img[B_DIM];

    if (tid < BC) {
        float fsum_t = 0.f, fm1 = 0.f, fsd2 = 0.f, fmxt = 0.f;
#pragma unroll
        for (int sg = 0; sg < SEGS; ++sg) {
            const float4 v = ws[(tid << 4) + sg];
            fsum_t += v.x; fm1 += v.y; fsd2 += v.z; fmxt = fmaxf(fmxt, v.w);
        }
        bool inactive = false;
        if (fmxt == 0.f) {
            // Rare path: slice's target is all-zero; must consult max_positiones.
            const float4* m4 = (const float4*)maxp + (size_t)tid * (HW / 4);
            float mx = 0.f;
            for (int i = 0; i < HW / 4; ++i) {
                const float4 v = m4[i];
                mx = fmaxf(mx, fmaxf(fmaxf(v.x, v.y), fmaxf(v.z, v.w)));
            }
            inactive = (mx == 0.f);
        }
        const float fm2 = fsd2 - fm1;
        const float d1 = fsum_t;
        const float d2 = (float)HW - fsum_t;
        const float loss = ALPHA * fm1 / (d1 + SMOOTH)
                         + (1.f - ALPHA) * fm2 / (d2 + SMOOTH);
        losses[tid] = inactive ? 0.f : loss;
    }
    __syncthreads();
    if (tid < B_DIM) {
        float sum = 0.f; int cnt = 0;
#pragma unroll
        for (int c = 0; c < C_DIM; ++c) {
            const float l = losses[tid * C_DIM + c];
            sum += l;
            cnt += (l != 0.f) ? 1 : 0;
        }
        img[tid] = sum / (float)cnt;   // 0/0 -> NaN matches reference
    }
    __syncthreads();
    if (tid == 0) {
        float sum = 0.f;
#pragma unroll
        for (int b = 0; b < B_DIM; ++b) sum += img[b];
        out[0] = sum / (float)B_DIM;
    }
}

// ---- fallback two-kernel path (used only if ws_size lacks the counter) ----

__global__ __launch_bounds__(TPB, 2) void mismatch_passA(
    const float* __restrict__ net_out,
    const float* __restrict__ target,
    float4* __restrict__ ws)
{
    const int blk = blockIdx.x;
    const size_t base4 = (size_t)blk * (SEG_ELEMS / 4);
    const int tid = threadIdx.x;

    const f32x4* __restrict__ t4 = (const f32x4*)target + base4;
    const f32x4* __restrict__ n4 = (const f32x4*)net_out + base4;

    float sum_t = 0.f, m1 = 0.f, sd2 = 0.f, mxt = 0.f;

#pragma unroll
    for (int k = 0; k < F4PT; ++k) {
        const int idx = k * TPB + tid;
        const f32x4 tv = __builtin_nontemporal_load(t4 + idx);
        const f32x4 nv = __builtin_nontemporal_load(n4 + idx);
#define ACC(c) { float t = tv.c, n = nv.c;                \
                 float d = t - n; float d2 = d * d;       \
                 sum_t += t; sd2 += d2;                   \
                 m1 = fmaf(d2, t, m1); mxt = fmaxf(mxt, t); }
        ACC(x) ACC(y) ACC(z) ACC(w)
#undef ACC
    }

#pragma unroll
    for (int off = 32; off > 0; off >>= 1) {
        sum_t += __shfl_down(sum_t, off);
        m1    += __shfl_down(m1, off);
        sd2   += __shfl_down(sd2, off);
        mxt    = fmaxf(mxt, __shfl_down(mxt, off));
    }

    __shared__ float s[4][4];
    const int wave = tid >> 6, lane = tid & 63;
    if (lane == 0) { s[wave][0] = sum_t; s[wave][1] = m1; s[wave][2] = sd2; s[wave][3] = mxt; }
    __syncthreads();
    if (tid == 0) {
        float4 o;
        o.x = s[0][0] + s[1][0] + s[2][0] + s[3][0];
        o.y = s[0][1] + s[1][1] + s[2][1] + s[3][1];
        o.z = s[0][2] + s[1][2] + s[2][2] + s[3][2];
        o.w = fmaxf(fmaxf(s[0][3], s[1][3]), fmaxf(s[2][3], s[3][3]));
        ws[blk] = o;
    }
}

__global__ __launch_bounds__(128) void mismatch_final(
    const float4* __restrict__ ws,
    const float* __restrict__ maxp,
    float* __restrict__ out)
{
    __shared__ float losses[BC];
    __shared__ float img[B_DIM];
    const int tid = threadIdx.x;

    {
        float sum_t = 0.f, m1 = 0.f, sd2 = 0.f, mxt = 0.f;
#pragma unroll
        for (int sg = 0; sg < SEGS; ++sg) {
            const float4 v = ws[(tid << 4) + sg];
            sum_t += v.x; m1 += v.y; sd2 += v.z; mxt = fmaxf(mxt, v.w);
        }
        bool inactive = false;
        if (mxt == 0.f) {
            const float4* m4 = (const float4*)maxp + (size_t)tid * (HW / 4);
            float mx = 0.f;
            for (int i = 0; i < HW / 4; ++i) {
                const float4 v = m4[i];
                mx = fmaxf(mx, fmaxf(fmaxf(v.x, v.y), fmaxf(v.z, v.w)));
            }
            inactive = (mx == 0.f);
        }
        const float m2 = sd2 - m1;
        const float d1 = sum_t;
        const float d2 = (float)HW - sum_t;
        const float loss = ALPHA * m1 / (d1 + SMOOTH)
                         + (1.f - ALPHA) * m2 / (d2 + SMOOTH);
        losses[tid] = inactive ? 0.f : loss;
    }
    __syncthreads();
    if (tid < B_DIM) {
        float sum = 0.f; int cnt = 0;
#pragma unroll
        for (int c = 0; c < C_DIM; ++c) {
            const float l = losses[tid * C_DIM + c];
            sum += l;
            cnt += (l != 0.f) ? 1 : 0;
        }
        img[tid] = sum / (float)cnt;
    }
    __syncthreads();
    if (tid == 0) {
        float sum = 0.f;
#pragma unroll
        for (int b = 0; b < B_DIM; ++b) sum += img[b];
        out[0] = sum / (float)B_DIM;
    }
}

extern "C" void kernel_launch(void* const* d_in, const int* in_sizes, int n_in,
                              void* d_out, int out_size, void* d_ws, size_t ws_size,
                              hipStream_t stream) {
    const float* net_out = (const float*)d_in[0];
    const float* target  = (const float*)d_in[1];
    const float* maxp    = (const float*)d_in[2];
    float* out = (float*)d_out;
    float4* ws = (float4*)d_ws;

    const size_t need = (size_t)NBLK * sizeof(float4) + sizeof(unsigned int);
    if (ws_size >= need) {
        unsigned int* counter =
            (unsigned int*)((char*)d_ws + (size_t)NBLK * sizeof(float4));
        hipMemsetAsync(counter, 0, sizeof(unsigned int), stream);
        mismatch_fused<<<NBLK, TPB, 0, stream>>>(net_out, target, maxp, ws, counter, out);
    } else {
        mismatch_passA<<<NBLK, TPB, 0, stream>>>(net_out, target, ws);
        mismatch_final<<<1, 128, 0, stream>>>(ws, maxp, out);
    }
}

// Round 2
// 183.403 us; speedup vs baseline: 1.5589x; 1.5589x over previous
//
#include <hip/hip_runtime.h>

// B=8, C=16, H=W=384. Inputs (fp32): net_out, target, max_positiones.
// loss_bc = 0.05*m1/(d1+eps) + 0.95*m2/(d2+eps)
//   m1 = sum(d2*t), d1 = sum(t), m2 = sum(d2) - m1, d2den = HW - d1
// active_bc = !(max(t)==0 && max(mp)==0) -> mp scanned only if max(t)==0 (rare)
// img_loss_b = sum_c(losses)/count_nonzero(losses); out = mean_b.
//
// R8: REVERT the R7 fusion. rocprof showed mismatch_fused = 131us with
// VALUBusy 2.6% / HBM 7% -> ~90us idle tail from 2048 serialized device-scope
// atomicAdds + per-block __threadfence (L2 writeback on CDNA4). Completion-
// counter fusion is wrong at this block count; two-kernel path restored.
// Single delta vs R6: SEGS 16->36 (2048 -> 4608 blocks, F4PT 9->4). Theory:
// 2048 blocks = exactly one residency wave (8 blk/CU) -> unamortized
// ramp/drain; 4608 blocks = 2.25 waves smooths it. R7 also showed half the
// reads hit L3 (FETCH 75.5MB for 151MB read), so passA's ~42us is well under
// the bandwidth roofline and worth one block-count probe.

typedef float f32x4 __attribute__((ext_vector_type(4)));

#define B_DIM 8
#define C_DIM 16
#define BC    (B_DIM * C_DIM)        // 128
#define HW    147456                 // 384*384
#define TPB   256

#define ALPHA  0.05f
#define SMOOTH 1e-6f

// ws layout: float4 per block: {sum_t, m1, sum_d2, mx_t}

template <int SEGS>
__global__ __launch_bounds__(TPB, 2) void mismatch_passA(
    const float* __restrict__ net_out,
    const float* __restrict__ target,
    float4* __restrict__ ws)
{
    constexpr int SEG_ELEMS = HW / SEGS;
    constexpr int F4PT = SEG_ELEMS / 4 / TPB;   // float4 per thread per array
    static_assert(SEG_ELEMS * SEGS == HW, "SEGS must divide HW");
    static_assert(F4PT * 4 * TPB == SEG_ELEMS, "TPB*4 must divide SEG_ELEMS");

    const int blk = blockIdx.x;                       // [0, BC*SEGS)
    const size_t base4 = (size_t)blk * (SEG_ELEMS / 4);
    const int tid = threadIdx.x;

    const f32x4* __restrict__ t4 = (const f32x4*)target + base4;
    const f32x4* __restrict__ n4 = (const f32x4*)net_out + base4;

    float sum_t = 0.f, m1 = 0.f, sd2 = 0.f, mxt = 0.f;

#pragma unroll
    for (int k = 0; k < F4PT; ++k) {
        const int idx = k * TPB + tid;   // coalesced float4 access
        const f32x4 tv = __builtin_nontemporal_load(t4 + idx);
        const f32x4 nv = __builtin_nontemporal_load(n4 + idx);
#define ACC(c) { float t = tv.c, n = nv.c;                \
                 float d = t - n; float d2 = d * d;       \
                 sum_t += t; sd2 += d2;                   \
                 m1 = fmaf(d2, t, m1); mxt = fmaxf(mxt, t); }
        ACC(x) ACC(y) ACC(z) ACC(w)
#undef ACC
    }

    // wave (64-lane) reduction
#pragma unroll
    for (int off = 32; off > 0; off >>= 1) {
        sum_t += __shfl_down(sum_t, off);
        m1    += __shfl_down(m1, off);
        sd2   += __shfl_down(sd2, off);
        mxt    = fmaxf(mxt, __shfl_down(mxt, off));
    }

    __shared__ float s[4][4];
    const int wave = tid >> 6, lane = tid & 63;
    if (lane == 0) { s[wave][0] = sum_t; s[wave][1] = m1; s[wave][2] = sd2; s[wave][3] = mxt; }
    __syncthreads();
    if (tid == 0) {
        float4 o;
        o.x = s[0][0] + s[1][0] + s[2][0] + s[3][0];
        o.y = s[0][1] + s[1][1] + s[2][1] + s[3][1];
        o.z = s[0][2] + s[1][2] + s[2][2] + s[3][2];
        o.w = fmaxf(fmaxf(s[0][3], s[1][3]), fmaxf(s[2][3], s[3][3]));
        ws[blk] = o;
    }
}

template <int SEGS>
__global__ __launch_bounds__(128) void mismatch_final(
    const float4* __restrict__ ws,
    const float* __restrict__ maxp,
    float* __restrict__ out)
{
    __shared__ float losses[BC];
    __shared__ float img[B_DIM];
    const int tid = threadIdx.x;   // one thread per (b,c) slice

    {
        float sum_t = 0.f, m1 = 0.f, sd2 = 0.f, mxt = 0.f;
#pragma unroll
        for (int sg = 0; sg < SEGS; ++sg) {
            const float4 v = ws[tid * SEGS + sg];
            sum_t += v.x; m1 += v.y; sd2 += v.z; mxt = fmaxf(mxt, v.w);
        }
        bool inactive = false;
        if (mxt == 0.f) {
            // Rare path: slice's target is all-zero; must consult max_positiones.
            const float4* m4 = (const float4*)maxp + (size_t)tid * (HW / 4);
            float mx = 0.f;
            for (int i = 0; i < HW / 4; ++i) {
                const float4 v = m4[i];
                mx = fmaxf(mx, fmaxf(fmaxf(v.x, v.y), fmaxf(v.z, v.w)));
            }
            inactive = (mx == 0.f);
        }
        const float m2 = sd2 - m1;
        const float d1 = sum_t;
        const float d2 = (float)HW - sum_t;
        const float loss = ALPHA * m1 / (d1 + SMOOTH)
                         + (1.f - ALPHA) * m2 / (d2 + SMOOTH);
        losses[tid] = inactive ? 0.f : loss;
    }
    __syncthreads();
    if (tid < B_DIM) {
        float s = 0.f; int cnt = 0;
#pragma unroll
        for (int c = 0; c < C_DIM; ++c) {
            const float l = losses[tid * C_DIM + c];
            s += l;
            cnt += (l != 0.f) ? 1 : 0;
        }
        img[tid] = s / (float)cnt;   // 0/0 -> NaN matches reference
    }
    __syncthreads();
    if (tid == 0) {
        float s = 0.f;
#pragma unroll
        for (int b = 0; b < B_DIM; ++b) s += img[b];
        out[0] = s / (float)B_DIM;
    }
}

extern "C" void kernel_launch(void* const* d_in, const int* in_sizes, int n_in,
                              void* d_out, int out_size, void* d_ws, size_t ws_size,
                              hipStream_t stream) {
    const float* net_out = (const float*)d_in[0];
    const float* target  = (const float*)d_in[1];
    const float* maxp    = (const float*)d_in[2];
    float* out = (float*)d_out;
    float4* ws = (float4*)d_ws;

    // Preferred geometry: SEGS=36 (4608 blocks, needs 73,728 B of ws).
    // Fall back to the proven SEGS=16 geometry (32,768 B) if ws is small.
    if (ws_size >= (size_t)BC * 36 * sizeof(float4)) {
        mismatch_passA<36><<<BC * 36, TPB, 0, stream>>>(net_out, target, ws);
        mismatch_final<36><<<1, 128, 0, stream>>>(ws, maxp, out);
    } else {
        mismatch_passA<16><<<BC * 16, TPB, 0, stream>>>(net_out, target, ws);
        mismatch_final<16><<<1, 128, 0, stream>>>(ws, maxp, out);
    }
}